// Round 8
// baseline (486.964 us; speedup 1.0000x reference)
//
#include <hip/hip_runtime.h>
#include <math.h>

#define DIN 512
#define HID 128
#define DOUT 20
#define NCAT 160          // 128 xl1 | 20 ms0 | 1 er1 | 11 pad
#define NBLK_COL 200
#define SCAN_TILE 1024

typedef unsigned int u32;
typedef unsigned short u16;
using short8 = __attribute__((ext_vector_type(8))) short;
using f32x4  = __attribute__((ext_vector_type(4))) float;

__device__ __forceinline__ u16 f2bf(float f) {   // RNE float->bf16
  u32 u = __float_as_uint(f);
  u += 0x7FFFu + ((u >> 16) & 1u);
  return (u16)(u >> 16);
}
__device__ __forceinline__ float bf2f(u16 h) {
  return __uint_as_float(((u32)h) << 16);
}

// ---------- prep: vr1 = W1r^T @ a1r  (512), vr2 = W2r^T @ a2r (128) ----------
__global__ void k_prep(const float* __restrict__ W1r, const float* __restrict__ a1r,
                       const float* __restrict__ W2r, const float* __restrict__ a2r,
                       float* __restrict__ vr1, float* __restrict__ vr2) {
  int t = threadIdx.x;
  for (int k = t; k < DIN; k += 256) {
    float s = 0.f;
    for (int c = 0; c < HID; ++c) s = fmaf(a1r[c], W1r[c * DIN + k], s);
    vr1[k] = s;
  }
  if (t < HID) {
    float s = 0.f;
    for (int c = 0; c < DOUT; ++c) s = fmaf(a2r[c], W2r[c * HID + t], s);
    vr2[t] = s;
  }
}

// ---------- build Wcat = [W1l; W0; vr1; pad] as bf16 hi/lo [160][512] ----------
__global__ void k_prepw(const float* __restrict__ W1l, const float* __restrict__ W0,
                        const float* __restrict__ vr1, u16* __restrict__ whcat,
                        u16* __restrict__ wlcat) {
  int idx = blockIdx.x * 256 + threadIdx.x;     // 160*512 = 81920
  if (idx >= NCAT * DIN) return;
  int c = idx >> 9, k = idx & 511;
  float w = 0.f;
  if (c < HID) w = W1l[c * DIN + k];
  else if (c < HID + DOUT) w = W0[(c - HID) * DIN + k];
  else if (c == HID + DOUT) w = vr1[k];
  u16 h = f2bf(w);
  whcat[idx] = h;
  wlcat[idx] = f2bf(w - bf2f(h));
}

// ---------- CSR build: histogram ----------
__global__ void k_hist(const int* __restrict__ ei, int* __restrict__ deg, int E) {
  int stride = gridDim.x * blockDim.x;
  for (int e = blockIdx.x * blockDim.x + threadIdx.x; e < E; e += stride)
    atomicAdd(deg + ei[E + e], 1);
}

// ---------- parallel scan phase 1: per-tile (1024 elems) sums ----------
__launch_bounds__(256)
__global__ void k_scan1(const int* __restrict__ deg, int* __restrict__ tilesum, int M) {
  __shared__ int ws[4];
  int t = threadIdx.x;
  int idx = blockIdx.x * SCAN_TILE + t * 4;
  int4 d = make_int4(0, 0, 0, 0);
  if (idx + 3 < M) d = *(const int4*)(deg + idx);
  else {
    if (idx + 0 < M) d.x = deg[idx + 0];
    if (idx + 1 < M) d.y = deg[idx + 1];
    if (idx + 2 < M) d.z = deg[idx + 2];
    if (idx + 3 < M) d.w = deg[idx + 3];
  }
  int s = d.x + d.y + d.z + d.w;
#pragma unroll
  for (int m = 1; m < 64; m <<= 1) s += __shfl_xor(s, m);
  int lane = t & 63, wave = t >> 6;
  if (lane == 0) ws[wave] = s;
  __syncthreads();
  if (t == 0) tilesum[blockIdx.x] = ws[0] + ws[1] + ws[2] + ws[3];
}

// ---------- scan phase 2: one wave scans <=64 tile sums; writes rowptr[M] ----------
__global__ void k_scan2(const int* __restrict__ tilesum, int* __restrict__ tileoff,
                        int* __restrict__ rowptr, int nb, int M) {
  int t = threadIdx.x;                 // 64 threads
  int own = (t < nb) ? tilesum[t] : 0;
  int v = own;
#pragma unroll
  for (int off = 1; off < 64; off <<= 1) {
    int u = __shfl_up(v, off);
    if (t >= off) v += u;
  }
  if (t < nb) tileoff[t] = v - own;    // exclusive
  if (t == nb - 1) rowptr[M] = v;      // total edge count
}

// ---------- scan phase 3: per-tile block scan + tile offset ----------
__launch_bounds__(256)
__global__ void k_scan3(const int* __restrict__ deg, const int* __restrict__ tileoff,
                        int* __restrict__ rowptr, int* __restrict__ cursor, int M) {
  __shared__ int wsums[4];
  int t = threadIdx.x;
  int idx = blockIdx.x * SCAN_TILE + t * 4;
  int4 d = make_int4(0, 0, 0, 0);
  if (idx + 3 < M) d = *(const int4*)(deg + idx);
  else {
    if (idx + 0 < M) d.x = deg[idx + 0];
    if (idx + 1 < M) d.y = deg[idx + 1];
    if (idx + 2 < M) d.z = deg[idx + 2];
    if (idx + 3 < M) d.w = deg[idx + 3];
  }
  int s0 = d.x, s01 = d.x + d.y, s012 = s01 + d.z, tsum = s012 + d.w;
  int lane = t & 63, wave = t >> 6;
  int v = tsum;
#pragma unroll
  for (int off = 1; off < 64; off <<= 1) {
    int u = __shfl_up(v, off);
    if (lane >= off) v += u;
  }
  if (lane == 63) wsums[wave] = v;
  __syncthreads();
  int woff = 0;
  for (int i = 0; i < wave; ++i) woff += wsums[i];
  int ex = tileoff[blockIdx.x] + woff + (v - tsum);
  if (idx + 0 < M) { rowptr[idx + 0] = ex;        cursor[idx + 0] = ex; }
  if (idx + 1 < M) { rowptr[idx + 1] = ex + s0;   cursor[idx + 1] = ex + s0; }
  if (idx + 2 < M) { rowptr[idx + 2] = ex + s01;  cursor[idx + 2] = ex + s01; }
  if (idx + 3 < M) { rowptr[idx + 3] = ex + s012; cursor[idx + 3] = ex + s012; }
}

// ---------- CSR build: bucket srcs by dst ----------
__global__ void k_csr(const int* __restrict__ ei, int* __restrict__ cursor,
                      int* __restrict__ csr_src, int E) {
  int stride = gridDim.x * blockDim.x;
  for (int e = blockIdx.x * blockDim.x + threadIdx.x; e < E; e += stride) {
    int d = ei[E + e];
    int p = atomicAdd(cursor + d, 1);
    csr_src[p] = ei[e];
  }
}

// ---------- fused MFMA GEMM, LDS-free: [xl1 | ms0 | er1] = x @ Wcat^T ----------
// Per-lane direct fragment loads: A from x (fp32->bf16 hi/lo in-register),
// B from whcat/wlcat (L2-resident, 320 KB). No __shared__, no barriers.
// Block = 4 waves: (wr,wc) in {0,1}x{0,1}; wave computes 32 rows x 80 cols.
__launch_bounds__(256, 4)
__global__ void k_fused1(const float* __restrict__ x, const u16* __restrict__ whcat,
                         const u16* __restrict__ wlcat, const float* __restrict__ b0,
                         float* __restrict__ xl1, float* __restrict__ ms0,
                         float* __restrict__ er1, int M) {
  const int tid  = threadIdx.x;
  const int wid  = tid >> 6;
  const int wr   = wid >> 1;          // row half: 0..1 (32 rows each)
  const int wc   = wid & 1;           // col half: 0..1 (80 cols each)
  const int lane = tid & 63;
  const int r    = lane & 15;
  const int g    = lane >> 4;
  const int brow = blockIdx.x * 64;
  const int colb = wc * 80;

  f32x4 acc[2][5];
#pragma unroll
  for (int mr = 0; mr < 2; ++mr)
#pragma unroll
    for (int nf = 0; nf < 5; ++nf)
      acc[mr][nf] = (f32x4){0.f, 0.f, 0.f, 0.f};

  for (int kt = 0; kt < DIN / 32; ++kt) {
    const int k0 = kt * 32;
    // A fragments: 8 fp32 per (mr), convert to bf16 hi/lo in-register
    short8 ah[2], alo[2];
#pragma unroll
    for (int mr = 0; mr < 2; ++mr) {
      const int row = brow + wr * 32 + mr * 16 + r;
      float4 v0 = make_float4(0.f, 0.f, 0.f, 0.f), v1 = v0;
      if (row < M) {
        const float* p = x + (size_t)row * DIN + k0 + g * 8;
        v0 = *(const float4*)p;
        v1 = *(const float4*)(p + 4);
      }
      float f[8] = {v0.x, v0.y, v0.z, v0.w, v1.x, v1.y, v1.z, v1.w};
      short8 hi, lo;
#pragma unroll
      for (int j = 0; j < 8; ++j) {
        u16 h = f2bf(f[j]);
        hi[j] = (short)h;
        lo[j] = (short)f2bf(f[j] - bf2f(h));
      }
      ah[mr] = hi;
      alo[mr] = lo;
    }
    // B fragments direct from L2; MFMA order per acc unchanged (hi*bh, hi*blo, lo*bh)
#pragma unroll
    for (int nf = 0; nf < 5; ++nf) {
      const size_t wrow = (size_t)(colb + nf * 16 + r) * DIN + k0 + g * 8;
      short8 bh  = *(const short8*)(whcat + wrow);
      short8 blo = *(const short8*)(wlcat + wrow);
#pragma unroll
      for (int mr = 0; mr < 2; ++mr) {
        acc[mr][nf] = __builtin_amdgcn_mfma_f32_16x16x32_bf16(ah[mr],  bh,  acc[mr][nf], 0, 0, 0);
        acc[mr][nf] = __builtin_amdgcn_mfma_f32_16x16x32_bf16(ah[mr],  blo, acc[mr][nf], 0, 0, 0);
        acc[mr][nf] = __builtin_amdgcn_mfma_f32_16x16x32_bf16(alo[mr], bh,  acc[mr][nf], 0, 0, 0);
      }
    }
  }

  // epilogue: C[row=(g*4+q)+16*mr+32*wr][col=r+16*nf+80*wc]
#pragma unroll
  for (int mr = 0; mr < 2; ++mr) {
    int growb = brow + wr * 32 + mr * 16 + g * 4;
#pragma unroll
    for (int nf = 0; nf < 5; ++nf) {
      int gcol = colb + nf * 16 + r;
#pragma unroll
      for (int q = 0; q < 4; ++q) {
        int grow = growb + q;
        if (grow < M) {
          float v = acc[mr][nf][q];
          if (gcol < HID) xl1[(size_t)grow * HID + gcol] = v;
          else if (gcol < HID + DOUT) ms0[(size_t)grow * DOUT + (gcol - HID)] = v + b0[gcol - HID];
          else if (gcol == HID + DOUT) er1[grow] = v;
        }
      }
    }
  }
}

// ---------- el1 = xl1 @ a1l ----------
__launch_bounds__(256)
__global__ void k_el1(const float* __restrict__ xl1, const float* __restrict__ a1l,
                      float* __restrict__ el1, int M) {
  int wv = threadIdx.x >> 6, lane = threadIdx.x & 63;
  int node = blockIdx.x * 4 + wv;
  if (node >= M) return;
  float2 v = *(const float2*)(xl1 + (size_t)node * HID + lane * 2);
  float2 a = *(const float2*)(a1l + lane * 2);
  float s = fmaf(v.y, a.y, v.x * a.x);
#pragma unroll
  for (int m = 1; m < 64; m <<= 1) s += __shfl_xor(s, m);
  if (lane == 0) el1[node] = s;
}

// ---------- gather layer 1 ----------
__launch_bounds__(256)
__global__ void k_gath1(const int* __restrict__ rowptr, const int* __restrict__ csr_src,
                        const float* __restrict__ el, const float* __restrict__ er,
                        const float* __restrict__ xl1, float* __restrict__ out1, int M) {
  int g = threadIdx.x >> 6, lane = threadIdx.x & 63;
  int d = blockIdx.x * 4 + g;
  if (d >= M) return;
  int lo = rowptr[d], hi = rowptr[d + 1];
  float erd = er[d];
  float a0 = 0.f, a1 = 0.f, wsum = 0.f;
  for (int j = lo; j < hi; ++j) {
    int s = csr_src[j];
    float v = el[s] + erd;
    v = v >= 0.f ? v : 0.2f * v;
    float w = expf(v);
    wsum += w;
    float2 xv = *(const float2*)(xl1 + (size_t)s * HID + lane * 2);
    a0 = fmaf(w, xv.x, a0);
    a1 = fmaf(w, xv.y, a1);
  }
  float inv = 1.f / (wsum + 1e-16f);
  *(float2*)(out1 + (size_t)d * HID + lane * 2) = make_float2(a0 * inv, a1 * inv);
}

// ---------- per-node layer 2 ----------
__launch_bounds__(256)
__global__ void k_node2(const float* __restrict__ out1, const float* __restrict__ b1,
                        const float* __restrict__ W2l, const float* __restrict__ a2l,
                        const float* __restrict__ vr2, float* __restrict__ xl2,
                        float* __restrict__ el2, float* __restrict__ er2, int M) {
  int g = threadIdx.x >> 5, lane = threadIdx.x & 31;
  int node = blockIdx.x * 8 + g;
  if (node >= M) return;
  float4 v = *(const float4*)(out1 + (size_t)node * HID + lane * 4);
  float4 bb = *(const float4*)(b1 + lane * 4);
  float h[4] = {v.x + bb.x, v.y + bb.y, v.z + bb.z, v.w + bb.w};
#pragma unroll
  for (int t = 0; t < 4; ++t) h[t] = h[t] > 0.f ? h[t] : expm1f(h[t]);
  float s[21];
#pragma unroll
  for (int j = 0; j < 21; ++j) {
    const float* wr = (j < 20) ? (W2l + (size_t)j * HID) : vr2;
    float4 wv = *(const float4*)(wr + lane * 4);
    float acc;
    acc = fmaf(h[0], wv.x, 0.f);
    acc = fmaf(h[1], wv.y, acc);
    acc = fmaf(h[2], wv.z, acc);
    acc = fmaf(h[3], wv.w, acc);
#pragma unroll
    for (int m = 1; m < 32; m <<= 1) acc += __shfl_xor(acc, m);
    s[j] = acc;
  }
  if (lane == 0) {
    float el = 0.f;
#pragma unroll
    for (int j = 0; j < 20; ++j) {
      xl2[(size_t)node * DOUT + j] = s[j];
      el = fmaf(s[j], a2l[j], el);
    }
    el2[node] = el;
    er2[node] = s[20];
  }
}

// ---------- gather layer 2 ----------
__launch_bounds__(256)
__global__ void k_gath2(const int* __restrict__ rowptr, const int* __restrict__ csr_src,
                        const float* __restrict__ el, const float* __restrict__ er,
                        const float* __restrict__ xl2, float* __restrict__ out2, int M) {
  int g = threadIdx.x >> 5, lane = threadIdx.x & 31;
  int d = blockIdx.x * 8 + g;
  if (d >= M) return;
  int lo = rowptr[d], hi = rowptr[d + 1];
  float erd = er[d];
  float acc = 0.f, wsum = 0.f;
  for (int j = lo; j < hi; ++j) {
    int s = csr_src[j];
    float v = el[s] + erd;
    v = v >= 0.f ? v : 0.2f * v;
    float w = expf(v);
    wsum += w;
    if (lane < DOUT) acc = fmaf(w, xl2[(size_t)s * DOUT + lane], acc);
  }
  if (lane < DOUT) out2[(size_t)d * DOUT + lane] = acc / (wsum + 1e-16f);
}

// ---------- column sum of exp(ms0) ----------
__launch_bounds__(256)
__global__ void k_colsum1(const float* __restrict__ ms0, float* __restrict__ partial, int M) {
  __shared__ float lds[4][20];
  float sm[20];
#pragma unroll
  for (int j = 0; j < 20; ++j) sm[j] = 0.f;
  int stride = gridDim.x * blockDim.x;
  for (int i = blockIdx.x * blockDim.x + threadIdx.x; i < M; i += stride) {
    const float4* row = (const float4*)(ms0 + (size_t)i * DOUT);
#pragma unroll
    for (int q = 0; q < 5; ++q) {
      float4 v = row[q];
      sm[q * 4 + 0] += expf(v.x);
      sm[q * 4 + 1] += expf(v.y);
      sm[q * 4 + 2] += expf(v.z);
      sm[q * 4 + 3] += expf(v.w);
    }
  }
#pragma unroll
  for (int j = 0; j < 20; ++j) {
#pragma unroll
    for (int k = 1; k < 64; k <<= 1) sm[j] += __shfl_xor(sm[j], k);
  }
  int wave = threadIdx.x >> 6, lane = threadIdx.x & 63;
  if (lane == 0) {
#pragma unroll
    for (int j = 0; j < 20; ++j) lds[wave][j] = sm[j];
  }
  __syncthreads();
  if (threadIdx.x < 20)
    partial[blockIdx.x * 20 + threadIdx.x] =
        lds[0][threadIdx.x] + lds[1][threadIdx.x] + lds[2][threadIdx.x] + lds[3][threadIdx.x];
}

__global__ void k_colsum2(const float* __restrict__ partial, float* __restrict__ colsum) {
  int j = threadIdx.x;
  if (j < 20) {
    float s = 0.f;
    for (int b = 0; b < NBLK_COL; ++b) s += partial[b * 20 + j];
    colsum[j] = s;
  }
}

// ---------- final ----------
__launch_bounds__(256)
__global__ void k_final(const float* __restrict__ ms0, const float* __restrict__ out2,
                        const float* __restrict__ b2, const float* __restrict__ colsum,
                        float* __restrict__ out, int M) {
  int i = blockIdx.x * 256 + threadIdx.x;
  if (i >= M) return;
  float ms1[20];
  const float4* r2 = (const float4*)(out2 + (size_t)i * DOUT);
#pragma unroll
  for (int q = 0; q < 5; ++q) {
    float4 v = r2[q];
    ms1[q * 4 + 0] = v.x + b2[q * 4 + 0];
    ms1[q * 4 + 1] = v.y + b2[q * 4 + 1];
    ms1[q * 4 + 2] = v.z + b2[q * 4 + 2];
    ms1[q * 4 + 3] = v.w + b2[q * 4 + 3];
  }
  float rmax = -INFINITY;
#pragma unroll
  for (int j = 0; j < 20; ++j) rmax = fmaxf(rmax, ms1[j]);
  float rsum = 0.f;
#pragma unroll
  for (int j = 0; j < 20; ++j) { ms1[j] = expf(ms1[j] - rmax); rsum += ms1[j]; }
  const float4* r0 = (const float4*)(ms0 + (size_t)i * DOUT);
  float o[20];
#pragma unroll
  for (int q = 0; q < 5; ++q) {
    float4 v = r0[q];
    o[q * 4 + 0] = expf(v.x) / colsum[q * 4 + 0] * (ms1[q * 4 + 0] / rsum);
    o[q * 4 + 1] = expf(v.y) / colsum[q * 4 + 1] * (ms1[q * 4 + 1] / rsum);
    o[q * 4 + 2] = expf(v.z) / colsum[q * 4 + 2] * (ms1[q * 4 + 2] / rsum);
    o[q * 4 + 3] = expf(v.w) / colsum[q * 4 + 3] * (ms1[q * 4 + 3] / rsum);
  }
  float4* po = (float4*)(out + (size_t)i * DOUT);
#pragma unroll
  for (int q = 0; q < 5; ++q)
    po[q] = make_float4(o[q * 4 + 0], o[q * 4 + 1], o[q * 4 + 2], o[q * 4 + 3]);
}

extern "C" void kernel_launch(void* const* d_in, const int* in_sizes, int n_in,
                              void* d_out, int out_size, void* d_ws, size_t ws_size,
                              hipStream_t stream) {
  const float* x   = (const float*)d_in[0];
  const int*   ei  = (const int*)d_in[1];
  const float* W0  = (const float*)d_in[2];
  const float* b0  = (const float*)d_in[3];
  const float* W1l = (const float*)d_in[4];
  const float* W1r = (const float*)d_in[5];
  const float* a1l = (const float*)d_in[6];
  const float* a1r = (const float*)d_in[7];
  const float* b1  = (const float*)d_in[8];
  const float* W2l = (const float*)d_in[9];
  const float* W2r = (const float*)d_in[10];
  const float* a2l = (const float*)d_in[11];
  const float* a2r = (const float*)d_in[12];
  const float* b2  = (const float*)d_in[13];
  const int M = in_sizes[0] / DIN;   // 50000
  const int E = in_sizes[1] / 2;     // 500000
  const int NB_SCAN = (M + SCAN_TILE - 1) / SCAN_TILE;   // 49 (<=64 required)
  (void)n_in; (void)out_size; (void)ws_size;

  char* w = (char*)d_ws;
  size_t off = 0;
  auto alloc = [&](size_t bytes) -> void* {
    void* p = w + off;
    off += (bytes + 255) & ~(size_t)255;
    return p;
  };
  float* xl1     = (float*)alloc((size_t)M * HID * 4);
  float* el1     = (float*)alloc((size_t)M * 4);
  float* er1     = (float*)alloc((size_t)M * 4);
  float* ms0     = (float*)alloc((size_t)M * DOUT * 4);
  float* out1    = (float*)alloc((size_t)M * HID * 4);
  float* xl2     = (float*)alloc((size_t)M * DOUT * 4);
  float* el2     = (float*)alloc((size_t)M * 4);
  float* er2     = (float*)alloc((size_t)M * 4);
  float* out2    = (float*)alloc((size_t)M * DOUT * 4);
  float* partial = (float*)alloc((size_t)NBLK_COL * 20 * 4);
  float* colsum  = (float*)alloc(32 * 4);
  float* vr1     = (float*)alloc(DIN * 4);
  float* vr2     = (float*)alloc(HID * 4);
  u16*   whcat   = (u16*)alloc((size_t)NCAT * DIN * 2);
  u16*   wlcat   = (u16*)alloc((size_t)NCAT * DIN * 2);
  int*   deg     = (int*)alloc((size_t)M * 4);
  int*   rowptr  = (int*)alloc((size_t)(M + 1) * 4);
  int*   cursor  = (int*)alloc((size_t)M * 4);
  int*   csr_src = (int*)alloc((size_t)E * 4);
  int*   tilesum = (int*)alloc(64 * 4);
  int*   tileoff = (int*)alloc(64 * 4);

  hipMemsetAsync(deg, 0, (size_t)M * 4, stream);

  k_prep<<<1, 256, 0, stream>>>(W1r, a1r, W2r, a2r, vr1, vr2);
  k_prepw<<<(NCAT * DIN + 255) / 256, 256, 0, stream>>>(W1l, W0, vr1, whcat, wlcat);
  k_hist<<<1024, 256, 0, stream>>>(ei, deg, E);
  k_scan1<<<NB_SCAN, 256, 0, stream>>>(deg, tilesum, M);
  k_scan2<<<1, 64, 0, stream>>>(tilesum, tileoff, rowptr, NB_SCAN, M);
  k_scan3<<<NB_SCAN, 256, 0, stream>>>(deg, tileoff, rowptr, cursor, M);
  k_csr<<<1024, 256, 0, stream>>>(ei, cursor, csr_src, E);

  k_fused1<<<(M + 63) / 64, 256, 0, stream>>>(x, whcat, wlcat, b0, xl1, ms0, er1, M);
  k_el1<<<(M + 3) / 4, 256, 0, stream>>>(xl1, a1l, el1, M);

  k_gath1<<<(M + 3) / 4, 256, 0, stream>>>(rowptr, csr_src, el1, er1, xl1, out1, M);
  k_node2<<<(M + 7) / 8, 256, 0, stream>>>(out1, b1, W2l, a2l, vr2, xl2, el2, er2, M);
  k_gath2<<<(M + 7) / 8, 256, 0, stream>>>(rowptr, csr_src, el2, er2, xl2, out2, M);

  k_colsum1<<<NBLK_COL, 256, 0, stream>>>(ms0, partial, M);
  k_colsum2<<<1, 64, 0, stream>>>(partial, colsum);
  k_final<<<(M + 255) / 256, 256, 0, stream>>>(ms0, out2, b2, colsum, (float*)d_out, M);
}

// Round 9
// 477.997 us; speedup vs baseline: 1.0188x; 1.0188x over previous
//
#include <hip/hip_runtime.h>
#include <math.h>

#define DIN 512
#define HID 128
#define DOUT 20
#define NCAT 160          // 128 xl1 | 20 ms0 | 1 er1 | 11 pad
#define BKP 40            // LDS row stride in ushorts (BK=32 + 8 pad)
#define NBLK_COL 200
#define SCAN_TILE 1024
#define NFRAG (10 * 16 * 64 * 8)   // ct * kt * lane * 8

typedef unsigned int u32;
typedef unsigned short u16;
using short8 = __attribute__((ext_vector_type(8))) short;
using f32x4  = __attribute__((ext_vector_type(4))) float;

__device__ __forceinline__ u16 f2bf(float f) {   // RNE float->bf16
  u32 u = __float_as_uint(f);
  u += 0x7FFFu + ((u >> 16) & 1u);
  return (u16)(u >> 16);
}
__device__ __forceinline__ float bf2f(u16 h) {
  return __uint_as_float(((u32)h) << 16);
}

// ---------- prep: vr1 = W1r^T @ a1r  (512), vr2 = W2r^T @ a2r (128) ----------
__global__ void k_prep(const float* __restrict__ W1r, const float* __restrict__ a1r,
                       const float* __restrict__ W2r, const float* __restrict__ a2r,
                       float* __restrict__ vr1, float* __restrict__ vr2) {
  int t = threadIdx.x;
  for (int k = t; k < DIN; k += 256) {
    float s = 0.f;
    for (int c = 0; c < HID; ++c) s = fmaf(a1r[c], W1r[c * DIN + k], s);
    vr1[k] = s;
  }
  if (t < HID) {
    float s = 0.f;
    for (int c = 0; c < DOUT; ++c) s = fmaf(a2r[c], W2r[c * HID + t], s);
    vr2[t] = s;
  }
}

// ---------- build Wcat in MFMA-fragment order, bf16 hi/lo ----------
// whf[((ct*16+kt)*64+lane)*8+j] = bf16( W[ct*16+(lane&15)][kt*32+(lane>>4)*8+j] )
__global__ void k_prepw(const float* __restrict__ W1l, const float* __restrict__ W0,
                        const float* __restrict__ vr1, u16* __restrict__ whf,
                        u16* __restrict__ wlf) {
  int idx = blockIdx.x * 256 + threadIdx.x;
  if (idx >= NFRAG) return;
  int j = idx & 7, lane = (idx >> 3) & 63, kt = (idx >> 9) & 15, ct = idx >> 13;
  int col = ct * 16 + (lane & 15);
  int k = kt * 32 + (lane >> 4) * 8 + j;
  float w = 0.f;
  if (col < HID) w = W1l[col * DIN + k];
  else if (col < HID + DOUT) w = W0[(col - HID) * DIN + k];
  else if (col == HID + DOUT) w = vr1[k];
  u16 h = f2bf(w);
  whf[idx] = h;
  wlf[idx] = f2bf(w - bf2f(h));
}

// ---------- CSR build: histogram ----------
__global__ void k_hist(const int* __restrict__ ei, int* __restrict__ deg, int E) {
  int stride = gridDim.x * blockDim.x;
  for (int e = blockIdx.x * blockDim.x + threadIdx.x; e < E; e += stride)
    atomicAdd(deg + ei[E + e], 1);
}

// ---------- parallel scan phase 1: per-tile (1024 elems) sums ----------
__launch_bounds__(256)
__global__ void k_scan1(const int* __restrict__ deg, int* __restrict__ tilesum, int M) {
  __shared__ int ws[4];
  int t = threadIdx.x;
  int idx = blockIdx.x * SCAN_TILE + t * 4;
  int4 d = make_int4(0, 0, 0, 0);
  if (idx + 3 < M) d = *(const int4*)(deg + idx);
  else {
    if (idx + 0 < M) d.x = deg[idx + 0];
    if (idx + 1 < M) d.y = deg[idx + 1];
    if (idx + 2 < M) d.z = deg[idx + 2];
    if (idx + 3 < M) d.w = deg[idx + 3];
  }
  int s = d.x + d.y + d.z + d.w;
#pragma unroll
  for (int m = 1; m < 64; m <<= 1) s += __shfl_xor(s, m);
  int lane = t & 63, wave = t >> 6;
  if (lane == 0) ws[wave] = s;
  __syncthreads();
  if (t == 0) tilesum[blockIdx.x] = ws[0] + ws[1] + ws[2] + ws[3];
}

// ---------- scan phase 2: one wave scans <=64 tile sums; writes rowptr[M] ----------
__global__ void k_scan2(const int* __restrict__ tilesum, int* __restrict__ tileoff,
                        int* __restrict__ rowptr, int nb, int M) {
  int t = threadIdx.x;                 // 64 threads
  int own = (t < nb) ? tilesum[t] : 0;
  int v = own;
#pragma unroll
  for (int off = 1; off < 64; off <<= 1) {
    int u = __shfl_up(v, off);
    if (t >= off) v += u;
  }
  if (t < nb) tileoff[t] = v - own;    // exclusive
  if (t == nb - 1) rowptr[M] = v;      // total edge count
}

// ---------- scan phase 3: per-tile block scan + tile offset ----------
__launch_bounds__(256)
__global__ void k_scan3(const int* __restrict__ deg, const int* __restrict__ tileoff,
                        int* __restrict__ rowptr, int* __restrict__ cursor, int M) {
  __shared__ int wsums[4];
  int t = threadIdx.x;
  int idx = blockIdx.x * SCAN_TILE + t * 4;
  int4 d = make_int4(0, 0, 0, 0);
  if (idx + 3 < M) d = *(const int4*)(deg + idx);
  else {
    if (idx + 0 < M) d.x = deg[idx + 0];
    if (idx + 1 < M) d.y = deg[idx + 1];
    if (idx + 2 < M) d.z = deg[idx + 2];
    if (idx + 3 < M) d.w = deg[idx + 3];
  }
  int s0 = d.x, s01 = d.x + d.y, s012 = s01 + d.z, tsum = s012 + d.w;
  int lane = t & 63, wave = t >> 6;
  int v = tsum;
#pragma unroll
  for (int off = 1; off < 64; off <<= 1) {
    int u = __shfl_up(v, off);
    if (lane >= off) v += u;
  }
  if (lane == 63) wsums[wave] = v;
  __syncthreads();
  int woff = 0;
  for (int i = 0; i < wave; ++i) woff += wsums[i];
  int ex = tileoff[blockIdx.x] + woff + (v - tsum);
  if (idx + 0 < M) { rowptr[idx + 0] = ex;        cursor[idx + 0] = ex; }
  if (idx + 1 < M) { rowptr[idx + 1] = ex + s0;   cursor[idx + 1] = ex + s0; }
  if (idx + 2 < M) { rowptr[idx + 2] = ex + s01;  cursor[idx + 2] = ex + s01; }
  if (idx + 3 < M) { rowptr[idx + 3] = ex + s012; cursor[idx + 3] = ex + s012; }
}

// ---------- CSR build: bucket srcs by dst ----------
__global__ void k_csr(const int* __restrict__ ei, int* __restrict__ cursor,
                      int* __restrict__ csr_src, int E) {
  int stride = gridDim.x * blockDim.x;
  for (int e = blockIdx.x * blockDim.x + threadIdx.x; e < E; e += stride) {
    int d = ei[E + e];
    int p = atomicAdd(cursor + d, 1);
    csr_src[p] = ei[e];
  }
}

// ---------- fused MFMA GEMM v3: A via LDS (coalesced), B direct from L2 ----------
// Block = 4 waves, BM=64. Wave w owns rows [brow+16w, brow+16w+16) x ALL 160 cols.
// B loads are packed-fragment (1 KB coalesced per frag). el1 folded into epilogue.
__launch_bounds__(256, 2)
__global__ void k_fused1(const float* __restrict__ x, const u16* __restrict__ whf,
                         const u16* __restrict__ wlf, const float* __restrict__ b0,
                         const float* __restrict__ a1l,
                         float* __restrict__ xl1, float* __restrict__ ms0,
                         float* __restrict__ er1, float* __restrict__ el1, int M) {
  __shared__ u16 xh_s[64 * BKP];
  __shared__ u16 xl_s[64 * BKP];
  const int tid  = threadIdx.x;
  const int wid  = tid >> 6;
  const int lane = tid & 63;
  const int r    = lane & 15;
  const int g    = lane >> 4;
  const int brow = blockIdx.x * 64;

  f32x4 acc[10];
#pragma unroll
  for (int ct = 0; ct < 10; ++ct) acc[ct] = (f32x4){0.f, 0.f, 0.f, 0.f};

  for (int kt = 0; kt < 16; ++kt) {
    const int k0 = kt * 32;
    __syncthreads();
    // stage x tile: 64 rows x 8 float4 = 512 slots (2/thread), fp32 -> bf16 hi/lo
#pragma unroll
    for (int i = 0; i < 2; ++i) {
      int s = i * 256 + tid;
      int row = s >> 3, c4 = s & 7;
      int grow = brow + row;
      float4 v = make_float4(0.f, 0.f, 0.f, 0.f);
      if (grow < M) v = *(const float4*)(x + (size_t)grow * DIN + k0 + c4 * 4);
      u16 h0 = f2bf(v.x), h1 = f2bf(v.y), h2 = f2bf(v.z), h3 = f2bf(v.w);
      *(ushort4*)&xh_s[row * BKP + c4 * 4] = make_ushort4(h0, h1, h2, h3);
      *(ushort4*)&xl_s[row * BKP + c4 * 4] =
          make_ushort4(f2bf(v.x - bf2f(h0)), f2bf(v.y - bf2f(h1)),
                       f2bf(v.z - bf2f(h2)), f2bf(v.w - bf2f(h3)));
    }
    __syncthreads();

    const int arow = wid * 16 + r;
    short8 ah  = *(const short8*)&xh_s[arow * BKP + g * 8];
    short8 alo = *(const short8*)&xl_s[arow * BKP + g * 8];

#pragma unroll
    for (int ct = 0; ct < 10; ++ct) {
      const size_t fb = (((size_t)ct * 16 + kt) * 64 + lane) * 8;
      short8 bh  = *(const short8*)(whf + fb);
      short8 blo = *(const short8*)(wlf + fb);
      acc[ct] = __builtin_amdgcn_mfma_f32_16x16x32_bf16(ah,  bh,  acc[ct], 0, 0, 0);
      acc[ct] = __builtin_amdgcn_mfma_f32_16x16x32_bf16(ah,  blo, acc[ct], 0, 0, 0);
      acc[ct] = __builtin_amdgcn_mfma_f32_16x16x32_bf16(alo, bh,  acc[ct], 0, 0, 0);
    }
  }

  // epilogue: C[row = brow+16*wid+g*4+q][col = ct*16+r]
  const int growb = brow + wid * 16 + g * 4;
#pragma unroll
  for (int ct = 0; ct < 10; ++ct) {
    int gcol = ct * 16 + r;
#pragma unroll
    for (int q = 0; q < 4; ++q) {
      int grow = growb + q;
      if (grow < M) {
        float v = acc[ct][q];
        if (gcol < HID) xl1[(size_t)grow * HID + gcol] = v;
        else if (gcol < HID + DOUT) ms0[(size_t)grow * DOUT + (gcol - HID)] = v + b0[gcol - HID];
        else if (gcol == HID + DOUT) er1[grow] = v;
      }
    }
  }
  // el1 = xl1 row . a1l, folded: partial over ct<8, reduce across the 16 r-lanes
  float part0 = 0.f, part1 = 0.f, part2 = 0.f, part3 = 0.f;
#pragma unroll
  for (int ct = 0; ct < 8; ++ct) {
    float a = a1l[ct * 16 + r];
    part0 = fmaf(acc[ct][0], a, part0);
    part1 = fmaf(acc[ct][1], a, part1);
    part2 = fmaf(acc[ct][2], a, part2);
    part3 = fmaf(acc[ct][3], a, part3);
  }
#pragma unroll
  for (int m = 1; m < 16; m <<= 1) {
    part0 += __shfl_xor(part0, m);
    part1 += __shfl_xor(part1, m);
    part2 += __shfl_xor(part2, m);
    part3 += __shfl_xor(part3, m);
  }
  if (r == 0) {
    if (growb + 0 < M) el1[growb + 0] = part0;
    if (growb + 1 < M) el1[growb + 1] = part1;
    if (growb + 2 < M) el1[growb + 2] = part2;
    if (growb + 3 < M) el1[growb + 3] = part3;
  }
}

// ---------- gather layer 1 ----------
__launch_bounds__(256)
__global__ void k_gath1(const int* __restrict__ rowptr, const int* __restrict__ csr_src,
                        const float* __restrict__ el, const float* __restrict__ er,
                        const float* __restrict__ xl1, float* __restrict__ out1, int M) {
  int g = threadIdx.x >> 6, lane = threadIdx.x & 63;
  int d = blockIdx.x * 4 + g;
  if (d >= M) return;
  int lo = rowptr[d], hi = rowptr[d + 1];
  float erd = er[d];
  float a0 = 0.f, a1 = 0.f, wsum = 0.f;
  for (int j = lo; j < hi; ++j) {
    int s = csr_src[j];
    float v = el[s] + erd;
    v = v >= 0.f ? v : 0.2f * v;
    float w = expf(v);
    wsum += w;
    float2 xv = *(const float2*)(xl1 + (size_t)s * HID + lane * 2);
    a0 = fmaf(w, xv.x, a0);
    a1 = fmaf(w, xv.y, a1);
  }
  float inv = 1.f / (wsum + 1e-16f);
  *(float2*)(out1 + (size_t)d * HID + lane * 2) = make_float2(a0 * inv, a1 * inv);
}

// ---------- per-node layer 2 ----------
__launch_bounds__(256)
__global__ void k_node2(const float* __restrict__ out1, const float* __restrict__ b1,
                        const float* __restrict__ W2l, const float* __restrict__ a2l,
                        const float* __restrict__ vr2, float* __restrict__ xl2,
                        float* __restrict__ el2, float* __restrict__ er2, int M) {
  int g = threadIdx.x >> 5, lane = threadIdx.x & 31;
  int node = blockIdx.x * 8 + g;
  if (node >= M) return;
  float4 v = *(const float4*)(out1 + (size_t)node * HID + lane * 4);
  float4 bb = *(const float4*)(b1 + lane * 4);
  float h[4] = {v.x + bb.x, v.y + bb.y, v.z + bb.z, v.w + bb.w};
#pragma unroll
  for (int t = 0; t < 4; ++t) h[t] = h[t] > 0.f ? h[t] : expm1f(h[t]);
  float s[21];
#pragma unroll
  for (int j = 0; j < 21; ++j) {
    const float* wr = (j < 20) ? (W2l + (size_t)j * HID) : vr2;
    float4 wv = *(const float4*)(wr + lane * 4);
    float acc;
    acc = fmaf(h[0], wv.x, 0.f);
    acc = fmaf(h[1], wv.y, acc);
    acc = fmaf(h[2], wv.z, acc);
    acc = fmaf(h[3], wv.w, acc);
#pragma unroll
    for (int m = 1; m < 32; m <<= 1) acc += __shfl_xor(acc, m);
    s[j] = acc;
  }
  if (lane == 0) {
    float el = 0.f;
#pragma unroll
    for (int j = 0; j < 20; ++j) {
      xl2[(size_t)node * DOUT + j] = s[j];
      el = fmaf(s[j], a2l[j], el);
    }
    el2[node] = el;
    er2[node] = s[20];
  }
}

// ---------- gather layer 2 ----------
__launch_bounds__(256)
__global__ void k_gath2(const int* __restrict__ rowptr, const int* __restrict__ csr_src,
                        const float* __restrict__ el, const float* __restrict__ er,
                        const float* __restrict__ xl2, float* __restrict__ out2, int M) {
  int g = threadIdx.x >> 5, lane = threadIdx.x & 31;
  int d = blockIdx.x * 8 + g;
  if (d >= M) return;
  int lo = rowptr[d], hi = rowptr[d + 1];
  float erd = er[d];
  float acc = 0.f, wsum = 0.f;
  for (int j = lo; j < hi; ++j) {
    int s = csr_src[j];
    float v = el[s] + erd;
    v = v >= 0.f ? v : 0.2f * v;
    float w = expf(v);
    wsum += w;
    if (lane < DOUT) acc = fmaf(w, xl2[(size_t)s * DOUT + lane], acc);
  }
  if (lane < DOUT) out2[(size_t)d * DOUT + lane] = acc / (wsum + 1e-16f);
}

// ---------- column sum of exp(ms0) ----------
__launch_bounds__(256)
__global__ void k_colsum1(const float* __restrict__ ms0, float* __restrict__ partial, int M) {
  __shared__ float lds[4][20];
  float sm[20];
#pragma unroll
  for (int j = 0; j < 20; ++j) sm[j] = 0.f;
  int stride = gridDim.x * blockDim.x;
  for (int i = blockIdx.x * blockDim.x + threadIdx.x; i < M; i += stride) {
    const float4* row = (const float4*)(ms0 + (size_t)i * DOUT);
#pragma unroll
    for (int q = 0; q < 5; ++q) {
      float4 v = row[q];
      sm[q * 4 + 0] += expf(v.x);
      sm[q * 4 + 1] += expf(v.y);
      sm[q * 4 + 2] += expf(v.z);
      sm[q * 4 + 3] += expf(v.w);
    }
  }
#pragma unroll
  for (int j = 0; j < 20; ++j) {
#pragma unroll
    for (int k = 1; k < 64; k <<= 1) sm[j] += __shfl_xor(sm[j], k);
  }
  int wave = threadIdx.x >> 6, lane = threadIdx.x & 63;
  if (lane == 0) {
#pragma unroll
    for (int j = 0; j < 20; ++j) lds[wave][j] = sm[j];
  }
  __syncthreads();
  if (threadIdx.x < 20)
    partial[blockIdx.x * 20 + threadIdx.x] =
        lds[0][threadIdx.x] + lds[1][threadIdx.x] + lds[2][threadIdx.x] + lds[3][threadIdx.x];
}

__global__ void k_colsum2(const float* __restrict__ partial, float* __restrict__ colsum) {
  int j = threadIdx.x;
  if (j < 20) {
    float s = 0.f;
    for (int b = 0; b < NBLK_COL; ++b) s += partial[b * 20 + j];
    colsum[j] = s;
  }
}

// ---------- final ----------
__launch_bounds__(256)
__global__ void k_final(const float* __restrict__ ms0, const float* __restrict__ out2,
                        const float* __restrict__ b2, const float* __restrict__ colsum,
                        float* __restrict__ out, int M) {
  int i = blockIdx.x * 256 + threadIdx.x;
  if (i >= M) return;
  float ms1[20];
  const float4* r2 = (const float4*)(out2 + (size_t)i * DOUT);
#pragma unroll
  for (int q = 0; q < 5; ++q) {
    float4 v = r2[q];
    ms1[q * 4 + 0] = v.x + b2[q * 4 + 0];
    ms1[q * 4 + 1] = v.y + b2[q * 4 + 1];
    ms1[q * 4 + 2] = v.z + b2[q * 4 + 2];
    ms1[q * 4 + 3] = v.w + b2[q * 4 + 3];
  }
  float rmax = -INFINITY;
#pragma unroll
  for (int j = 0; j < 20; ++j) rmax = fmaxf(rmax, ms1[j]);
  float rsum = 0.f;
#pragma unroll
  for (int j = 0; j < 20; ++j) { ms1[j] = expf(ms1[j] - rmax); rsum += ms1[j]; }
  const float4* r0 = (const float4*)(ms0 + (size_t)i * DOUT);
  float o[20];
#pragma unroll
  for (int q = 0; q < 5; ++q) {
    float4 v = r0[q];
    o[q * 4 + 0] = expf(v.x) / colsum[q * 4 + 0] * (ms1[q * 4 + 0] / rsum);
    o[q * 4 + 1] = expf(v.y) / colsum[q * 4 + 1] * (ms1[q * 4 + 1] / rsum);
    o[q * 4 + 2] = expf(v.z) / colsum[q * 4 + 2] * (ms1[q * 4 + 2] / rsum);
    o[q * 4 + 3] = expf(v.w) / colsum[q * 4 + 3] * (ms1[q * 4 + 3] / rsum);
  }
  float4* po = (float4*)(out + (size_t)i * DOUT);
#pragma unroll
  for (int q = 0; q < 5; ++q)
    po[q] = make_float4(o[q * 4 + 0], o[q * 4 + 1], o[q * 4 + 2], o[q * 4 + 3]);
}

extern "C" void kernel_launch(void* const* d_in, const int* in_sizes, int n_in,
                              void* d_out, int out_size, void* d_ws, size_t ws_size,
                              hipStream_t stream) {
  const float* x   = (const float*)d_in[0];
  const int*   ei  = (const int*)d_in[1];
  const float* W0  = (const float*)d_in[2];
  const float* b0  = (const float*)d_in[3];
  const float* W1l = (const float*)d_in[4];
  const float* W1r = (const float*)d_in[5];
  const float* a1l = (const float*)d_in[6];
  const float* a1r = (const float*)d_in[7];
  const float* b1  = (const float*)d_in[8];
  const float* W2l = (const float*)d_in[9];
  const float* W2r = (const float*)d_in[10];
  const float* a2l = (const float*)d_in[11];
  const float* a2r = (const float*)d_in[12];
  const float* b2  = (const float*)d_in[13];
  const int M = in_sizes[0] / DIN;   // 50000
  const int E = in_sizes[1] / 2;     // 500000
  const int NB_SCAN = (M + SCAN_TILE - 1) / SCAN_TILE;   // 49 (<=64 required)
  (void)n_in; (void)out_size; (void)ws_size;

  char* w = (char*)d_ws;
  size_t off = 0;
  auto alloc = [&](size_t bytes) -> void* {
    void* p = w + off;
    off += (bytes + 255) & ~(size_t)255;
    return p;
  };
  float* xl1     = (float*)alloc((size_t)M * HID * 4);
  float* el1     = (float*)alloc((size_t)M * 4);
  float* er1     = (float*)alloc((size_t)M * 4);
  float* ms0     = (float*)alloc((size_t)M * DOUT * 4);
  float* out1    = (float*)alloc((size_t)M * HID * 4);
  float* xl2     = (float*)alloc((size_t)M * DOUT * 4);
  float* el2     = (float*)alloc((size_t)M * 4);
  float* er2     = (float*)alloc((size_t)M * 4);
  float* out2    = (float*)alloc((size_t)M * DOUT * 4);
  float* partial = (float*)alloc((size_t)NBLK_COL * 20 * 4);
  float* colsum  = (float*)alloc(32 * 4);
  float* vr1     = (float*)alloc(DIN * 4);
  float* vr2     = (float*)alloc(HID * 4);
  u16*   whf     = (u16*)alloc((size_t)NFRAG * 2);
  u16*   wlf     = (u16*)alloc((size_t)NFRAG * 2);
  int*   deg     = (int*)alloc((size_t)M * 4);
  int*   rowptr  = (int*)alloc((size_t)(M + 1) * 4);
  int*   cursor  = (int*)alloc((size_t)M * 4);
  int*   csr_src = (int*)alloc((size_t)E * 4);
  int*   tilesum = (int*)alloc(64 * 4);
  int*   tileoff = (int*)alloc(64 * 4);

  hipMemsetAsync(deg, 0, (size_t)M * 4, stream);

  k_prep<<<1, 256, 0, stream>>>(W1r, a1r, W2r, a2r, vr1, vr2);
  k_prepw<<<(NFRAG + 255) / 256, 256, 0, stream>>>(W1l, W0, vr1, whf, wlf);
  k_hist<<<1024, 256, 0, stream>>>(ei, deg, E);
  k_scan1<<<NB_SCAN, 256, 0, stream>>>(deg, tilesum, M);
  k_scan2<<<1, 64, 0, stream>>>(tilesum, tileoff, rowptr, NB_SCAN, M);
  k_scan3<<<NB_SCAN, 256, 0, stream>>>(deg, tileoff, rowptr, cursor, M);
  k_csr<<<1024, 256, 0, stream>>>(ei, cursor, csr_src, E);

  k_fused1<<<(M + 63) / 64, 256, 0, stream>>>(x, whf, wlf, b0, a1l,
                                              xl1, ms0, er1, el1, M);

  k_gath1<<<(M + 3) / 4, 256, 0, stream>>>(rowptr, csr_src, el1, er1, xl1, out1, M);
  k_node2<<<(M + 7) / 8, 256, 0, stream>>>(out1, b1, W2l, a2l, vr2, xl2, el2, er2, M);
  k_gath2<<<(M + 7) / 8, 256, 0, stream>>>(rowptr, csr_src, el2, er2, xl2, out2, M);

  k_colsum1<<<NBLK_COL, 256, 0, stream>>>(ms0, partial, M);
  k_colsum2<<<1, 64, 0, stream>>>(partial, colsum);
  k_final<<<(M + 255) / 256, 256, 0, stream>>>(ms0, out2, b2, colsum, (float*)d_out, M);
}